// Round 8
// baseline (326.042 us; speedup 1.0000x reference)
//
#include <hip/hip_runtime.h>
#include <stdint.h>

// Problem: B=32, DIM=256, FMAP=32 (N=1024), HEADS=8, DK=32, DV=64
// Inputs/outputs are float32 (per reference); internal compute in bf16 MFMA.
// pos_indices (int32) unused: it is deterministically |dr|*32+|dc|.
//
// R15: BUGFIX of R14 — W staging in k_qkv wrote only 16 of its 32 ushorts
//   per thread (2xuint4 instead of 4xuint4), leaving half of each Aw row
//   unstaged -> absmax 40. Restored the 4x q4 loop. Everything else = R14.
// R14: xT round-trip ELIMINATED. k_qkv reads x f32 directly, transposing
//   during LDS staging with an XOR granule swizzle (write: ds_write_b32
//   2-way-free; read: lane-uniform granule XOR per fragment).
// R13: k_oconv BK=64 + LDS-transpose epilogue (kept).
// R12: DE-ATOMIZED stats (479->307us): race-free partials + reduction kernels.
// R11: k_qkv coalesced LDS-transpose store epilogue.
// R10: k_qkv 128x128 tiles.
// R8: BN fold into k_attn; h=bid&7 XCD swizzle keeps bias/K/V L2-hot.

typedef unsigned int uint;
typedef unsigned short ushort;

typedef __bf16 bf16x8 __attribute__((ext_vector_type(8)));
typedef short  shortx4 __attribute__((ext_vector_type(4)));
typedef float  floatx4 __attribute__((ext_vector_type(4)));

__device__ __forceinline__ float bf2f(ushort u){ uint t = ((uint)u)<<16; float f; __builtin_memcpy(&f,&t,4); return f; }
__device__ __forceinline__ ushort f2bf(float f){ uint u; __builtin_memcpy(&u,&f,4); return (ushort)((u + 0x7fffu + ((u>>16)&1u))>>16); }
__device__ __forceinline__ uint pack2(float a, float b){ return (uint)f2bf(a) | ((uint)f2bf(b)<<16); }
__device__ __forceinline__ uint fbits(float f){ uint u; __builtin_memcpy(&u,&f,4); return u; }
__device__ __forceinline__ float asf(uint u){ float f; __builtin_memcpy(&f,&u,4); return f; }
__device__ __forceinline__ uint4 cvt8(const float* p){
  float4 a = *(const float4*)p; float4 b = *(const float4*)(p+4);
  uint4 r; r.x = pack2(a.x,a.y); r.y = pack2(a.z,a.w); r.z = pack2(b.x,b.y); r.w = pack2(b.z,b.w);
  return r;
}

__device__ __forceinline__ floatx4 mfma32(bf16x8 a, bf16x8 b, floatx4 c){
  return __builtin_amdgcn_mfma_f32_16x16x32_bf16(a,b,c,0,0,0);
}
__device__ __forceinline__ floatx4 mfma16(shortx4 a, shortx4 b, floatx4 c){
  return __builtin_amdgcn_mfma_f32_16x16x16bf16_1k(a,b,c,0,0,0);
}

// ---------------- workspace layout (bytes) ----------------
// qb   [0,16.8M) | kb [16.8M,33.6M) | vt [33.6M,67.1M) | bias [67.1M,83.9M)
// wbf  [100.7M,101.2M)  (dead after k_qkv)
// sqk  [101.2M,105.4M)  float2[1024][512] qkv stat partials (dead GT tail;
//                       consumed by k_coef BEFORE k_attn writes GT)
// GT   [83.9M,117.4M)   bf16 [b][n][512] (written by k_attn)
// opre [0,16.8M)        (overlays qb after attn)
// soc  = kb region      float2[256][512] oconv stat partials (kb dead)
// oc   = OFF_OSUM       float[512] final-BN coefs
#define OFF_KB   16777216u
#define OFF_VT   33554432u
#define OFF_BIAS 67108864u
#define OFF_WBF  100663296u
#define OFF_SQK  101187584u
#define OFF_GT   83886080u
#define OFF_SUM  117440512u
#define OFF_OSUM 117448704u
#define OFF_AB   117450752u
#define WS_NEED  117460992u

// ---------------- K1: fused prep: Wqkv->bf16, bias table ----------------
__global__ __launch_bounds__(256) void k_prep(
    const float* __restrict__ Wq, const float* __restrict__ Wk, const float* __restrict__ Wv,
    const float* __restrict__ pt,
    ushort* __restrict__ wbf, ushort* __restrict__ bias){
  int bid = blockIdx.x;
  int tid = threadIdx.x;
  if (bid < 256){
    // Wq 65536 | Wk 65536 | Wv 131072 elements -> bf16
    int idx = (bid*256 + tid)*4;
    const float* src; int off;
    if (idx < 65536){ src = Wq; off = idx; }
    else if (idx < 131072){ src = Wk; off = idx - 65536; }
    else { src = Wv; off = idx - 131072; }
    float4 f = *(const float4*)(src + off);
    uint2 o; o.x = pack2(f.x,f.y); o.y = pack2(f.z,f.w);
    *(uint2*)(wbf + idx) = o;
  } else {
    // bias table, frag order [h][isub(64)][jsub(64)][lane(64)] x uint2
    int t = (bid-256)*256 + tid;   // 2^21
    int lane = t & 63;
    int jsub = (t>>6)&63;
    int isub = (t>>12)&63;
    int h = t>>18;
    int i  = isub*16 + (lane&15);
    int jb = jsub*16 + ((lane>>4)<<2);
    int r1 = i>>5, c1 = i&31;
    const float BS = 1.44269504088896f*5.65685424949238f;  // L2E/SCALE
    ushort o[4];
    #pragma unroll
    for(int r=0;r<4;r++){
      int j = jb + r;
      int dr = r1 - (j>>5); dr = dr<0 ? -dr : dr;
      int dc = c1 - (j&31); dc = dc<0 ? -dc : dc;
      o[r] = f2bf(pt[(dr*32+dc)*8 + h] * BS);
    }
    uint2 ow; ow.x = (uint)o[0] | ((uint)o[1]<<16); ow.y = (uint)o[2] | ((uint)o[3]<<16);
    ((uint2*)bias)[t] = ow;
  }
}

// ---------------- K2: QKV projection GEMM from x directly, 128x128 tiles ----------------
// grid 2048 = nt(8) x ot(8) x b(32); XCD = nt so all 8 ot-blocks sharing an
// x slab co-locate (x HBM-fetched once per element). x [b][c][n] f32 is
// transposed during staging into Ax[n][c] bf16 with granule swizzle:
//   granule g' = g ^ ((row>>4)&7); write key lane-computed, read key
//   lane-uniform per fragment (row = base16 + (l&15)). Writes 2-way (free).
// Stats: race-free partials sqk[ch][contrib]. NO atomics.
__global__ __launch_bounds__(256) void k_qkv(const float* __restrict__ x,
    const ushort* __restrict__ wbf,
    ushort* __restrict__ qb, ushort* __restrict__ kb, ushort* __restrict__ vt,
    float2* __restrict__ sqk){
  __shared__ ushort smem[18432];          // Ax [0,9216) | Aw [9216,18432) ushorts
  ushort* Ax = smem;
  ushort* Aw = smem + 9216;
  int bid = blockIdx.x;
  int nt = bid & 7; int ot = (bid>>3)&7; int b = bid>>6;
  int nb = nt*128, ob = ot*128;
  int mode = (ob < 256) ? 0 : (ob < 512 ? 1 : 2);
  int t = threadIdx.x, w = t>>6, l = t&63;
  int wr = w>>1, wc = w&1;
  // W staging (linear): row sr, 32-ushort half sc; 4x uint4 per thread
  int sr = t>>1, sc = (t&1)*32;
  const ushort* wrow = wbf + (size_t)(ob + sr)*256 + sc;
  // x staging (transpose + swizzle)
  int cp = t>>3;            // c-pair 0..31
  int ngx = (t&7)*16;       // n-base (row>>4 == t&7 for all 16 rows)
  int gsw = (((cp>>2) ^ (t&7))<<3) + ((cp&3)<<1);   // swizzled ushort off in row
  const float* xbase = x + (((size_t)b*256 + cp*2)<<10) + nb + ngx;

  floatx4 acc[4][4];
  #pragma unroll
  for(int m=0;m<4;m++)
    #pragma unroll
    for(int nf=0;nf<4;nf++) acc[m][nf] = (floatx4){0.f,0.f,0.f,0.f};

  for(int kc=0;kc<4;kc++){
    #pragma unroll
    for(int q4=0;q4<4;q4++){
      *(uint4*)&Aw[sr*72 + sc + q4*8] = *(const uint4*)(wrow + kc*64 + q4*8);
    }
    const float* xr = xbase + ((size_t)kc<<16);   // +kc*64 c-rows (64*1024 floats)
    #pragma unroll
    for(int hh=0;hh<2;hh++){
      float r0[8], r1[8];
      *(float4*)&r0[0] = *(const float4*)(xr + hh*8);
      *(float4*)&r0[4] = *(const float4*)(xr + hh*8 + 4);
      *(float4*)&r1[0] = *(const float4*)(xr + 1024 + hh*8);
      *(float4*)&r1[4] = *(const float4*)(xr + 1024 + hh*8 + 4);
      #pragma unroll
      for(int j=0;j<8;j++){
        *(uint*)&Ax[(ngx + hh*8 + j)*72 + gsw] = pack2(r0[j], r1[j]);
      }
    }
    __syncthreads();
    int gl = l>>4;
    int xrb = wr*64, wrb = wc*64;   // Ax rows are n (base wr*64); Aw rows are o (base wc*64)
    #pragma unroll
    for(int kk=0;kk<2;kk++){
      bf16x8 xf[4], wf[4];
      #pragma unroll
      for(int m=0;m<4;m++){
        int srow = (4*wr + m) & 7;                 // (row>>4)&7, lane-uniform
        int g2 = ((kk*4 + gl) ^ srow) << 3;
        xf[m] = *(const bf16x8*)&Ax[(xrb + m*16 + (l&15))*72 + g2];
      }
      #pragma unroll
      for(int nf=0;nf<4;nf++)
        wf[nf] = *(const bf16x8*)&Aw[(wrb + nf*16 + (l&15))*72 + kk*32 + gl*8];
      if (mode < 2){
        #pragma unroll
        for(int m=0;m<4;m++)
          #pragma unroll
          for(int nf=0;nf<4;nf++)
            acc[m][nf] = mfma32(xf[m], wf[nf], acc[m][nf]);   // C rows=n, cols=o
      } else {
        #pragma unroll
        for(int m=0;m<4;m++)
          #pragma unroll
          for(int nf=0;nf<4;nf++)
            acc[m][nf] = mfma32(wf[m], xf[nf], acc[m][nf]);   // C rows=o, cols=n
      }
    }
    __syncthreads();
  }

  int contrib = (nt*32 + b)*2 + wr;
  // ---- stat partials (register shuffles + race-free writes) ----
  if (mode < 2){
    #pragma unroll
    for(int nf=0;nf<4;nf++){
      int o = ob + wc*64 + nf*16 + (l&15);   // global channel (q:0-255, k:256-511)
      float s1=0.f, s2=0.f;
      #pragma unroll
      for(int m=0;m<4;m++){
        #pragma unroll
        for(int r=0;r<4;r++){
          float val = acc[m][nf][r];
          s1 += val; s2 += val*val;
        }
      }
      s1 += __shfl_xor(s1,16,64); s1 += __shfl_xor(s1,32,64);
      s2 += __shfl_xor(s2,16,64); s2 += __shfl_xor(s2,32,64);
      if (l < 16){
        float2 p; p.x = s1; p.y = s2;
        sqk[(size_t)o*512 + contrib] = p;
      }
    }
  } else {
    #pragma unroll
    for(int m=0;m<4;m++){
      #pragma unroll
      for(int r=0;r<4;r++){
        int o  = ob + wc*64 + m*16 + (l>>4)*4 + r;   // global 512..1023
        float s1=0.f, s2=0.f;
        #pragma unroll
        for(int nf=0;nf<4;nf++){
          float val = acc[m][nf][r];
          s1 += val; s2 += val*val;
        }
        s1 += __shfl_xor(s1,1,64); s1 += __shfl_xor(s1,2,64); s1 += __shfl_xor(s1,4,64); s1 += __shfl_xor(s1,8,64);
        s2 += __shfl_xor(s2,1,64); s2 += __shfl_xor(s2,2,64); s2 += __shfl_xor(s2,4,64); s2 += __shfl_xor(s2,8,64);
        if ((l&15)==0){
          float2 p; p.x = s1; p.y = s2;
          sqk[(size_t)o*512 + contrib] = p;
        }
      }
    }
  }

  // ---- epilogue: per-wave LDS transpose -> coalesced stores ----
  ushort* ep = smem + w*4608;
  if (mode < 2){
    #pragma unroll
    for(int m=0;m<4;m++)
      #pragma unroll
      for(int nf=0;nf<4;nf++){
        int lo = nf*16 + (l&15);
        #pragma unroll
        for(int r=0;r<4;r++){
          int ln = m*16 + (l>>4)*4 + r;
          ep[ln*72 + lo] = f2bf(acc[m][nf][r]);
        }
      }
    ushort* outb = (mode==0)? qb : kb;
    #pragma unroll
    for(int p=0;p<8;p++){
      int rr = p*8 + (l>>3);          // n-local
      int ci = (l&7)*8;               // o-local, 8-ch chunk
      uint4 v = *(const uint4*)&ep[rr*72 + ci];
      int n = nb + wr*64 + rr;
      int o = ob + wc*64 + ci;
      int oc = o & 255;
      int h = oc>>5, d = oc&31;
      *(uint4*)(outb + (((size_t)(b*8+h)<<10) + n)*32 + d) = v;
    }
  } else {
    #pragma unroll
    for(int m=0;m<4;m++)
      #pragma unroll
      for(int nf=0;nf<4;nf++){
        int ln = nf*16 + (l&15);
        #pragma unroll
        for(int r=0;r<4;r++){
          int lo = m*16 + (l>>4)*4 + r;
          ep[lo*72 + ln] = f2bf(acc[m][nf][r]);
        }
      }
    #pragma unroll
    for(int p=0;p<8;p++){
      int rr = p*8 + (l>>3);          // o-local
      int ci = (l&7)*8;               // n-local chunk
      uint4 v = *(const uint4*)&ep[rr*72 + ci];
      int o  = ob + wc*64 + rr;
      int ov = o - 512;
      int h = ov>>6, dv = ov&63;
      int n = nb + wr*64 + ci;
      *(uint4*)(vt + ((((size_t)b*8 + h)*64 + dv)<<10) + n) = v;
    }
  }
}

// ---------------- K3a: per-channel reduction + BN coefficients for q/k/v ----------------
__global__ __launch_bounds__(256) void k_coef(const float2* __restrict__ sqk,
    const float* gq, const float* bq, const float* gk, const float* bk,
    const float* gvp, const float* bvp, float* __restrict__ ab){
  __shared__ float red[4][2];
  int ch = blockIdx.x;
  int t = threadIdx.x, w = t>>6, l = t&63;
  float2 v0 = sqk[(size_t)ch*512 + t];
  float2 v1 = sqk[(size_t)ch*512 + 256 + t];
  float s1 = v0.x + v1.x, s2 = v0.y + v1.y;
  s1 += __shfl_xor(s1,1,64); s2 += __shfl_xor(s2,1,64);
  s1 += __shfl_xor(s1,2,64); s2 += __shfl_xor(s2,2,64);
  s1 += __shfl_xor(s1,4,64); s2 += __shfl_xor(s2,4,64);
  s1 += __shfl_xor(s1,8,64); s2 += __shfl_xor(s2,8,64);
  s1 += __shfl_xor(s1,16,64); s2 += __shfl_xor(s2,16,64);
  s1 += __shfl_xor(s1,32,64); s2 += __shfl_xor(s2,32,64);
  if (l==0){ red[w][0]=s1; red[w][1]=s2; }
  __syncthreads();
  if (t==0){
    float S1 = red[0][0]+red[1][0]+red[2][0]+red[3][0];
    float S2 = red[0][1]+red[1][1]+red[2][1]+red[3][1];
    float mean = S1 * (1.0f/32768.0f);
    float var  = S2 * (1.0f/32768.0f) - mean*mean;
    float inv  = rsqrtf(var + 1e-5f);
    float g, be, ex;
    if (ch < 256){ g = gq[ch]; be = bq[ch]; ex = 1.44269504088896f*0.17677669529664f; } // L2E*SCALE
    else if (ch < 512){ g = gk[ch-256]; be = bk[ch-256]; ex = 1.0f; }
    else { g = gvp[ch-512]; be = bvp[ch-512]; ex = 1.0f; }
    ab[ch*2]   = g*inv*ex;
    ab[ch*2+1] = (be - mean*g*inv)*ex;
  }
}

// q fragment prep: BN(q) then fold k's BN scale ak in; bk offset is dropped
// (constant along softmax rows -> cancels in P/l exactly).
__device__ __forceinline__ bf16x8 qprep(uint4 raw, const float* __restrict__ abq,
                                        const float* __restrict__ abk){
  uint w4[4] = {raw.x, raw.y, raw.z, raw.w};
  ushort o[8];
  #pragma unroll
  for(int p=0;p<4;p++){
    float lo = asf(w4[p]<<16), hi = asf(w4[p] & 0xffff0000u);
    float q0 = abq[p*4+0]*lo + abq[p*4+1];
    float q1 = abq[p*4+2]*hi + abq[p*4+3];
    o[p*2]   = f2bf(q0 * abk[p*4+0]);
    o[p*2+1] = f2bf(q1 * abk[p*4+2]);
  }
  bf16x8 r; __builtin_memcpy(&r, o, 16);
  return r;
}

// ---------------- K5: flash attention + fused q/k/v BN + gelu -> GT bf16 [b][n][512] ----------------
// (R12 structure — known good.) 2 i-strips per wave; l-sum via ones-MFMA.
// bid decode: h in 3 LSBs (XCD = h): per-XCD bias slice + K/V stay L2-hot.
__global__ __launch_bounds__(256) void k_attn(const ushort* __restrict__ qb, const ushort* __restrict__ kb,
    const ushort* __restrict__ vt, const ushort* __restrict__ bias,
    const float* __restrict__ ab, ushort* __restrict__ GT){
  __shared__ ushort smem[9216];       // kt [0,2560) + vtl [2560,7168); gbuf overlays [0,9216)
  ushort* kt  = smem;
  ushort* vtl = smem + 2560;
  ushort* gbuf = smem;
  int bid = blockIdx.x;
  int h = bid & 7;
  int itile = (bid>>3)&7;
  int b = bid>>6;
  int t = threadIdx.x, w = t>>6, l = t&63;
  int isub0 = itile*8 + w*2;          // two 16-row subtiles: isub0, isub0+1
  size_t bh = (size_t)b*8 + h;

  const float* abq = ab + (size_t)(h*32 + (l>>4)*8)*2;         // q BN coefs, 8 ch
  const float* abk = ab + (size_t)(256 + h*32 + (l>>4)*8)*2;   // k BN coefs (scale used)
  uint4 qr0 = *(const uint4*)(qb + ((bh<<10) + isub0*16 + (l&15))*32 + (l>>4)*8);
  uint4 qr1 = *(const uint4*)(qb + ((bh<<10) + (isub0+1)*16 + (l&15))*32 + (l>>4)*8);
  bf16x8 qf0 = qprep(qr0, abq, abk);
  bf16x8 qf1 = qprep(qr1, abq, abk);

  const shortx4 vones = { (short)0x3F80, (short)0x3F80, (short)0x3F80, (short)0x3F80 }; // bf16 1.0
  floatx4 lf0 = {0.f,0.f,0.f,0.f}, lf1 = {0.f,0.f,0.f,0.f};
  floatx4 O0[4] = {{0.f,0.f,0.f,0.f},{0.f,0.f,0.f,0.f},{0.f,0.f,0.f,0.f},{0.f,0.f,0.f,0.f}};
  floatx4 O1[4] = {{0.f,0.f,0.f,0.f},{0.f,0.f,0.f,0.f},{0.f,0.f,0.f,0.f},{0.f,0.f,0.f,0.f}};
  int sr = t>>2, scq = t&3;
  const uint2* bp0 = (const uint2*)bias + (((size_t)h*64 + isub0)*64)*64 + l;
  const uint2* bp1 = bp0 + 64*64;     // next isub

  for(int jt=0;jt<16;jt++){
    int jbase = jt*64;
    *(uint4*)&kt[sr*40 + scq*8] = *(const uint4*)(kb + ((bh<<10) + jbase + sr)*32 + scq*8);
    const ushort* vsrc = vt + ((bh*64 + sr)<<10) + jbase + scq*16;
    *(uint4*)&vtl[sr*72 + scq*16]     = *(const uint4*)vsrc;
    *(uint4*)&vtl[sr*72 + scq*16 + 8] = *(const uint4*)(vsrc + 8);
    __syncthreads();

    #pragma unroll
    for(int js=0;js<4;js++){
      uint2 bw0 = bp0[js*64];
      uint2 bw1 = bp1[js*64];
      bf16x8 kf = *(const bf16x8*)&kt[(js*16 + (l&15))*40 + (l>>4)*8];
      floatx4 c0 = { asf(bw0.x<<16), asf(bw0.x & 0xffff0000u), asf(bw0.y<<16), asf(bw0.y & 0xffff0000u) };
      floatx4 c1 = { asf(bw1.x<<16), asf(bw1.x & 0xffff0000u), asf(bw1.y<<16), asf(bw1.y & 0xffff0000u) };
      floatx4 S0 = mfma32(kf, qf0, c0);   // S^T tile (j rows, i cols), log2 domain
      floatx4 S1 = mfma32(kf, qf1, c1);
      float a0 = __builtin_amdgcn_exp2f(S0[0]);
      float a1 = __builtin_amdgcn_exp2f(S0[1]);
      float a2 = __builtin_amdgcn_exp2f(S0[2]);
      float a3 = __builtin_amdgcn_exp2f(S0[3]);
      float b0 = __builtin_amdgcn_exp2f(S1[0]);
      float b1 = __builtin_amdgcn_exp2f(S1[1]);
      float b2 = __builtin_amdgcn_exp2f(S1[2]);
      float b3 = __builtin_amdgcn_exp2f(S1[3]);
      uint2 pu0, pu1;
      pu0.x = __builtin_amdgcn_perm(fbits(a1), fbits(a0), 0x07060302u);
      pu0.y = __builtin_amdgcn_perm(fbits(a3), fbits(a2), 0x07060302u);
      pu1.x = __builtin_amdgcn_perm(fbits(b1), fbits(b0), 0x07060302u);
      pu1.y = __builtin_amdgcn_perm(fbits(b3), fbits(b2), 0x07060302u);
      shortx4 p0, p1;
      __builtin_memcpy(&p0, &pu0, 8);
      __builtin_memcpy(&p1, &pu1, 8);
      lf0 = mfma16(vones, p0, lf0);       // column-sums of P -> l per i (col=lane&15)
      lf1 = mfma16(vones, p1, lf1);
      #pragma unroll
      for(int d=0;d<4;d++){
        shortx4 vf = *(const shortx4*)&vtl[(d*16 + (l&15))*72 + js*16 + (l>>4)*4];
        O0[d] = mfma16(vf, p0, O0[d]);    // out^T[dv][i], raw v (BN in epilogue)
        O1[d] = mfma16(vf, p1, O1[d]);
      }
    }
    bp0 += 256; bp1 += 256;   // 4 js * 64 lanes
    __syncthreads();
  }

  float invl0 = 1.0f/lf0[0];   // every reg/row of lf holds the same column sum
  float invl1 = 1.0f/lf1[0];

  // epilogue: v-BN (av*(O/l)+bv via l linearity), gelu, reorganize via LDS
  #pragma unroll
  for(int ii=0;ii<2;ii++){
    float invl = ii ? invl1 : invl0;
    #pragma unroll
    for(int d=0;d<4;d++){
      floatx4 Ov = ii ? O1[d] : O0[d];
      const float* abv = ab + (size_t)(512 + h*64 + d*16 + (l>>4)*4)*2;
      float4 e01 = *(const float4*)abv;
      float4 e23 = *(const float4*)(abv + 4);
      float av[4] = {e01.x, e01.z, e23.x, e23.z};
      float bv[4] = {e01.y, e01.w, e23.y, e23.w};
      ushort gu[4];
      #pragma unroll
      for(int r=0;r<4;r++){
        float o = av[r]*(Ov[r]*invl) + bv[r];
        float g = 0.5f*o*(1.0f + erff(o*0.70710678118655f));
        gu[r] = f2bf(g);
      }
      uint2 gw; gw.x = (uint)gu[0] | ((uint)gu[1]<<16); gw.y = (uint)gu[2] | ((uint)gu[3]<<16);
      *(uint2*)&gbuf[w*2304 + (ii*16 + (l&15))*72 + d*16 + (l>>4)*4] = gw;
    }
  }
  __syncthreads();
  int ibase = itile*128 + w*32;
  #pragma unroll
  for(int p8=0;p8<4;p8++){
    int rl = (l>>3) + p8*8;
    int ck = l&7;
    uint4 g4 = *(uint4*)&gbuf[w*2304 + rl*72 + ck*8];
    int n = ibase + rl;
    *(uint4*)(GT + ((size_t)(b*1024 + n))*512 + h*64 + ck*8) = g4;
  }
}

// ---------------- K6: output conv + bias + stat partials (BK=64, NO atomics) ----------------
__global__ __launch_bounds__(256) void k_oconv(const ushort* __restrict__ GT, const float* __restrict__ Wo,
    const float* __restrict__ bo, ushort* __restrict__ opre, float2* __restrict__ soc){
  __shared__ ushort smem[18432];      // Aw [0,9216) | Ag [9216,18432)
  ushort* Aw = smem;
  ushort* Ag = smem + 9216;
  int bid = blockIdx.x;
  int nt = bid & 15; int ot = (bid>>4)&3; int b = bid>>6;
  int nb = nt*64, ob = ot*64;
  int t = threadIdx.x, w = t>>6, l = t&63;
  int sr = t>>2, sc = (t&3)*16;
  const float*  wsrc = Wo + (size_t)(ob + sr)*512 + sc;
  const ushort* gsrc = GT + ((size_t)b*1024 + nb + sr)*512 + sc;
  floatx4 acc[4] = {{0.f,0.f,0.f,0.f},{0.f,0.f,0.f,0.f},{0.f,0.f,0.f,0.f},{0.f,0.f,0.f,0.f}};
  for(int kc=0;kc<8;kc++){
    *(uint4*)&Aw[sr*72+sc]   = cvt8(wsrc + kc*64);
    *(uint4*)&Aw[sr*72+sc+8] = cvt8(wsrc + kc*64 + 8);
    *(uint4*)&Ag[sr*72+sc]   = *(const uint4*)(gsrc + kc*64);
    *(uint4*)&Ag[sr*72+sc+8] = *(const uint4*)(gsrc + kc*64 + 8);
    __syncthreads();
    #pragma unroll
    for(int kk=0;kk<2;kk++){
      bf16x8 af = *(const bf16x8*)&Aw[(w*16 + (l&15))*72 + kk*32 + (l>>4)*8];
      #pragma unroll
      for(int ns=0;ns<4;ns++){
        bf16x8 bfv = *(const bf16x8*)&Ag[(ns*16 + (l&15))*72 + kk*32 + (l>>4)*8];
        acc[ns] = mfma32(af, bfv, acc[ns]);
      }
    }
    __syncthreads();
  }
  // ---- stats + per-wave LDS transpose (Aw/Ag dead after final barrier) ----
  ushort* ep = smem + w*1152;          // 16 rows x 72 ushorts per wave
  int contrib = nt*32 + b;             // 512 contributors per channel
  #pragma unroll
  for(int r_=0;r_<4;r_++){
    int o = ob + w*16 + (l>>4)*4 + r_;
    float bias_o = bo[o];
    float s1=0.f, s2=0.f;
    #pragma unroll
    for(int ns=0;ns<4;ns++){
      float val = acc[ns][r_] + bias_o;
      ep[((l>>4)*4 + r_)*72 + ns*16 + (l&15)] = f2bf(val);
      s1 += val; s2 += val*val;
    }
    s1 += __shfl_xor(s1,1,64); s1 += __shfl_xor(s1,2,64); s1 += __shfl_xor(s1,4,64); s1 += __shfl_xor(s1,8,64);
    s2 += __shfl_xor(s2,1,64); s2 += __shfl_xor(s2,2,64); s2 += __shfl_xor(s2,4,64); s2 += __shfl_xor(s2,8,64);
    if ((l&15)==0){
      float2 p; p.x = s1; p.y = s2;
      soc[(size_t)o*512 + contrib] = p;
    }
  }
  // in-wave DS ordering -> no barrier needed; coalesced 2x16B stores per lane
  {
    int rr = l>>2, cseg = (l&3)*16;
    uint4 v0 = *(const uint4*)&ep[rr*72 + cseg];
    uint4 v1 = *(const uint4*)&ep[rr*72 + cseg + 8];
    int o = ob + w*16 + rr;
    ushort* dst = opre + (((size_t)(b*256+o))<<10) + nb + cseg;
    *(uint4*)dst     = v0;
    *(uint4*)(dst+8) = v1;
  }
}

// ---------------- K6b: per-channel reduction + final BN coefs ----------------
__global__ __launch_bounds__(256) void k_ocoef(const float2* __restrict__ soc,
    const float* __restrict__ go, const float* __restrict__ beo, float* __restrict__ oc){
  __shared__ float red[4][2];
  int ch = blockIdx.x;
  int t = threadIdx.x, w = t>>6, l = t&63;
  float2 v0 = soc[(size_t)ch*512 + t];
  float2 v1 = soc[(size_t)ch*512 + 256 + t];
  float s1 = v0.x + v1.x, s2 = v0.y + v1.y;
  s1 += __shfl_xor(s1,1,64); s2 += __shfl_xor(s2,1,64);
  s1 += __shfl_xor(s1,2,64); s2 += __shfl_xor(s2,2,64);
  s1 += __shfl_xor(s1,4,64); s2 += __shfl_xor(s2,4,64);
  s1 += __shfl_xor(s1,8,64); s2 += __shfl_xor(s2,8,64);
  s1 += __shfl_xor(s1,16,64); s2 += __shfl_xor(s2,16,64);
  s1 += __shfl_xor(s1,32,64); s2 += __shfl_xor(s2,32,64);
  if (l==0){ red[w][0]=s1; red[w][1]=s2; }
  __syncthreads();
  if (t==0){
    float S1 = red[0][0]+red[1][0]+red[2][0]+red[3][0];
    float S2 = red[0][1]+red[1][1]+red[2][1]+red[3][1];
    float mean = S1 * (1.0f/32768.0f);
    float var  = S2 * (1.0f/32768.0f) - mean*mean;
    float inv  = rsqrtf(var + 1e-5f);
    float a = go[ch]*inv;
    oc[ch*2]   = a;
    oc[ch*2+1] = beo[ch] - mean*a;
  }
}

// ---------------- K7: final BN apply (coefs precomputed; bf16 in, f32 out) ----------------
__global__ __launch_bounds__(256) void k_bnout(const ushort* __restrict__ opre, const float* __restrict__ oc,
    float* __restrict__ out){
  size_t e = ((size_t)blockIdx.x*256 + threadIdx.x)*4;
  int o = (int)((e>>10)&255);
  float a = oc[o*2], bb = oc[o*2+1];
  uint2 raw = *(const uint2*)(opre + e);
  float4 ov;
  ov.x = a*asf(raw.x<<16)           + bb;
  ov.y = a*asf(raw.x & 0xffff0000u) + bb;
  ov.z = a*asf(raw.y<<16)           + bb;
  ov.w = a*asf(raw.y & 0xffff0000u) + bb;
  *(float4*)(out + e) = ov;
}

extern "C" void kernel_launch(void* const* d_in, const int* in_sizes, int n_in,
                              void* d_out, int out_size, void* d_ws, size_t ws_size,
                              hipStream_t stream){
  (void)in_sizes; (void)n_in; (void)out_size;
  const float* x   = (const float*)d_in[0];
  const float* Wq  = (const float*)d_in[1];
  const float* gq  = (const float*)d_in[2];
  const float* bq  = (const float*)d_in[3];
  const float* Wk  = (const float*)d_in[4];
  const float* gk  = (const float*)d_in[5];
  const float* bk  = (const float*)d_in[6];
  const float* Wv  = (const float*)d_in[7];
  const float* gvp = (const float*)d_in[8];
  const float* bvp = (const float*)d_in[9];
  const float* Wo  = (const float*)d_in[10];
  const float* bo  = (const float*)d_in[11];
  const float* go  = (const float*)d_in[12];
  const float* beo = (const float*)d_in[13];
  const float* pt  = (const float*)d_in[14];
  // d_in[15] pos_indices: unused (recomputed analytically)

  char* ws = (char*)d_ws;
  if (ws_size < (size_t)WS_NEED) return;
  ushort* qb   = (ushort*)(ws);
  ushort* kb   = (ushort*)(ws + OFF_KB);
  ushort* vt   = (ushort*)(ws + OFF_VT);
  ushort* bias = (ushort*)(ws + OFF_BIAS);
  ushort* wbf  = (ushort*)(ws + OFF_WBF);
  ushort* GT   = (ushort*)(ws + OFF_GT);
  ushort* opre = (ushort*)(ws);
  float2* sqk  = (float2*)(ws + OFF_SQK);     // dead GT tail until k_attn
  float2* soc  = (float2*)(ws + OFF_KB);      // kb region, dead after k_attn
  float* oc    = (float*)(ws + OFF_OSUM);
  float* ab    = (float*)(ws + OFF_AB);

  k_prep<<<8448,256,0,stream>>>(Wq, Wk, Wv, pt, wbf, bias);
  k_qkv<<<2048,256,0,stream>>>(x, wbf, qb, kb, vt, sqk);
  k_coef<<<1024,256,0,stream>>>(sqk, gq, bq, gk, bk, gvp, bvp, ab);
  k_attn<<<2048,256,0,stream>>>(qb, kb, vt, bias, ab, GT);
  k_oconv<<<2048,256,0,stream>>>(GT, Wo, bo, opre, soc);
  k_ocoef<<<256,256,0,stream>>>(soc, go, beo, oc);
  k_bnout<<<8192,256,0,stream>>>(opre, oc, (float*)d_out);
}

// Round 9
// 306.814 us; speedup vs baseline: 1.0627x; 1.0627x over previous
//
#include <hip/hip_runtime.h>
#include <stdint.h>

// Problem: B=32, DIM=256, FMAP=32 (N=1024), HEADS=8, DK=32, DV=64
// Inputs/outputs are float32 (per reference); internal compute in bf16 MFMA.
// pos_indices (int32) unused: it is deterministically |dr|*32+|dc|.
//
// R16: REVERT k_prep/k_qkv to R12 xT versions (R14/R15 x-direct staging cost
//   more inside the latency-limited GEMM than the xT HBM round-trip saved:
//   307->326). k_attn: kt LDS staging dropped — K fragments read directly
//   from kb (L2-hot via h=bid&7 XCD pinning); removes 1 ds_write + 4 ds_read
//   per thread/tile and part of the 1.19e7 bank conflicts. vtl unchanged.
// R13: k_oconv BK=64 + LDS-transpose epilogue (kept). setprio rejected.
// R12: DE-ATOMIZED stats (479->307us): race-free partials + reduction kernels.
// R11: k_qkv coalesced LDS-transpose store epilogue.
// R10: k_qkv 128x128 tiles.
// R8: BN fold into k_attn; h=bid&7 XCD swizzle keeps bias/K/V L2-hot.

typedef unsigned int uint;
typedef unsigned short ushort;

typedef __bf16 bf16x8 __attribute__((ext_vector_type(8)));
typedef short  shortx4 __attribute__((ext_vector_type(4)));
typedef float  floatx4 __attribute__((ext_vector_type(4)));

__device__ __forceinline__ float bf2f(ushort u){ uint t = ((uint)u)<<16; float f; __builtin_memcpy(&f,&t,4); return f; }
__device__ __forceinline__ ushort f2bf(float f){ uint u; __builtin_memcpy(&u,&f,4); return (ushort)((u + 0x7fffu + ((u>>16)&1u))>>16); }
__device__ __forceinline__ uint pack2(float a, float b){ return (uint)f2bf(a) | ((uint)f2bf(b)<<16); }
__device__ __forceinline__ uint fbits(float f){ uint u; __builtin_memcpy(&u,&f,4); return u; }
__device__ __forceinline__ float asf(uint u){ float f; __builtin_memcpy(&f,&u,4); return f; }
__device__ __forceinline__ uint4 cvt8(const float* p){
  float4 a = *(const float4*)p; float4 b = *(const float4*)(p+4);
  uint4 r; r.x = pack2(a.x,a.y); r.y = pack2(a.z,a.w); r.z = pack2(b.x,b.y); r.w = pack2(b.z,b.w);
  return r;
}

__device__ __forceinline__ floatx4 mfma32(bf16x8 a, bf16x8 b, floatx4 c){
  return __builtin_amdgcn_mfma_f32_16x16x32_bf16(a,b,c,0,0,0);
}
__device__ __forceinline__ floatx4 mfma16(shortx4 a, shortx4 b, floatx4 c){
  return __builtin_amdgcn_mfma_f32_16x16x16bf16_1k(a,b,c,0,0,0);
}

// ---------------- workspace layout (bytes) ----------------
// qb   [0,16.8M) | kb [16.8M,33.6M) | vt [33.6M,67.1M) | bias [67.1M,83.9M)
// xT   [83.9M,100.7M) + wbf [100.7M,101.2M)  (dead after k_qkv)
// sqk  [101.2M,105.4M)  float2[1024][512] qkv stat partials (dead GT tail;
//                       consumed by k_coef BEFORE k_attn writes GT)
// GT   [83.9M,117.4M)   bf16 [b][n][512] (written by k_attn)
// opre [0,16.8M)        (overlays qb after attn)
// soc  = kb region      float2[256][512] oconv stat partials (kb dead)
// oc   = OFF_OSUM       float[512] final-BN coefs
#define OFF_KB   16777216u
#define OFF_VT   33554432u
#define OFF_BIAS 67108864u
#define OFF_XT   83886080u
#define OFF_WBF  100663296u
#define OFF_SQK  101187584u
#define OFF_GT   83886080u
#define OFF_SUM  117440512u
#define OFF_OSUM 117448704u
#define OFF_AB   117450752u
#define WS_NEED  117460992u

// ---------------- K1: fused prep: Wqkv->bf16, x transpose, bias table ----------------
__global__ __launch_bounds__(256) void k_prep(const float* __restrict__ x,
    const float* __restrict__ Wq, const float* __restrict__ Wk, const float* __restrict__ Wv,
    const float* __restrict__ pt,
    ushort* __restrict__ xT, ushort* __restrict__ wbf, ushort* __restrict__ bias){
  __shared__ ushort tr[64*66];
  int bid = blockIdx.x;
  int tid = threadIdx.x;
  if (bid < 256){
    int idx = (bid*256 + tid)*4;
    const float* src; int off;
    if (idx < 65536){ src = Wq; off = idx; }
    else if (idx < 131072){ src = Wk; off = idx - 65536; }
    else { src = Wv; off = idx - 131072; }
    float4 f = *(const float4*)(src + off);
    uint2 o; o.x = pack2(f.x,f.y); o.y = pack2(f.z,f.w);
    *(uint2*)(wbf + idx) = o;
  } else if (bid < 2304){
    int b2 = bid - 256;
    int cb = (b2 & 3)*64;
    int nb = ((b2>>2)&15)*64;
    int b  = b2>>6;
    int cl = tid>>2, n0 = (tid&3)*16;
    const float* src = x + (((size_t)b*256 + cb + cl)<<10) + nb + n0;
    ushort u16[16];
    #pragma unroll
    for(int q4=0;q4<4;q4++){
      float4 f = *(const float4*)(src + q4*4);
      u16[q4*4+0]=f2bf(f.x); u16[q4*4+1]=f2bf(f.y); u16[q4*4+2]=f2bf(f.z); u16[q4*4+3]=f2bf(f.w);
    }
    #pragma unroll
    for(int j=0;j<16;j++) tr[(n0+j)*66 + cl] = u16[j];
    __syncthreads();
    int nl = tid>>2, c0 = (tid&3)*16;
    uint o2[8];
    #pragma unroll
    for(int k=0;k<8;k++) o2[k] = *(const uint*)&tr[nl*66 + c0 + k*2];
    ushort* dst = xT + (((size_t)b*1024 + nb + nl)<<8) + cb + c0;
    *(uint4*)dst     = *(uint4*)&o2[0];
    *(uint4*)(dst+8) = *(uint4*)&o2[4];
  } else {
    int t = (bid-2304)*256 + tid;   // 2^21
    int lane = t & 63;
    int jsub = (t>>6)&63;
    int isub = (t>>12)&63;
    int h = t>>18;
    int i  = isub*16 + (lane&15);
    int jb = jsub*16 + ((lane>>4)<<2);
    int r1 = i>>5, c1 = i&31;
    const float BS = 1.44269504088896f*5.65685424949238f;  // L2E/SCALE
    ushort o[4];
    #pragma unroll
    for(int r=0;r<4;r++){
      int j = jb + r;
      int dr = r1 - (j>>5); dr = dr<0 ? -dr : dr;
      int dc = c1 - (j&31); dc = dc<0 ? -dc : dc;
      o[r] = f2bf(pt[(dr*32+dc)*8 + h] * BS);
    }
    uint2 ow; ow.x = (uint)o[0] | ((uint)o[1]<<16); ow.y = (uint)o[2] | ((uint)o[3]<<16);
    ((uint2*)bias)[t] = ow;
  }
}

// ---------------- K2: QKV projection GEMM, 128x128 tiles + stat partials ----------------
// grid 2048 = nt(8) x ot(8) x b(32). ob = ot*128 => block-uniform mode.
// v blocks swap MFMA operands so acc cols = n (transposed [b][h][dv][n] output).
// Stats: race-free partials sqk[ch][contrib], contrib=(nt*32+b)*2+wr. NO atomics.
__global__ __launch_bounds__(256) void k_qkv(const ushort* __restrict__ xT,
    const ushort* __restrict__ wbf,
    ushort* __restrict__ qb, ushort* __restrict__ kb, ushort* __restrict__ vt,
    float2* __restrict__ sqk){
  __shared__ ushort smem[18432];          // Ax [0,9216) | Aw [9216,18432) ushorts
  ushort* Ax = smem;
  ushort* Aw = smem + 9216;
  int bid = blockIdx.x;
  int nt = bid & 7; int ot = (bid>>3)&7; int b = bid>>6;
  int nb = nt*128, ob = ot*128;
  int mode = (ob < 256) ? 0 : (ob < 512 ? 1 : 2);
  int t = threadIdx.x, w = t>>6, l = t&63;
  int wr = w>>1, wc = w&1;
  int sr = t>>1, sc = (t&1)*32;
  const ushort* xrow = xT + (((size_t)b*1024 + nb + sr)<<8) + sc;
  const ushort* wrow = wbf + (size_t)(ob + sr)*256 + sc;
  floatx4 acc[4][4];
  #pragma unroll
  for(int m=0;m<4;m++)
    #pragma unroll
    for(int nf=0;nf<4;nf++) acc[m][nf] = (floatx4){0.f,0.f,0.f,0.f};

  for(int kc=0;kc<4;kc++){
    #pragma unroll
    for(int q4=0;q4<4;q4++){
      *(uint4*)&Ax[sr*72 + sc + q4*8] = *(const uint4*)(xrow + kc*64 + q4*8);
      *(uint4*)&Aw[sr*72 + sc + q4*8] = *(const uint4*)(wrow + kc*64 + q4*8);
    }
    __syncthreads();
    const ushort* Abuf = (mode==2)? Aw : Ax;   // first operand rows -> C rows
    const ushort* Bbuf = (mode==2)? Ax : Aw;   // second operand rows -> C cols
    int arb = (mode==2)? wc*64 : wr*64;
    int brb = (mode==2)? wr*64 : wc*64;
    #pragma unroll
    for(int kk=0;kk<2;kk++){
      bf16x8 af[4], bfr[4];
      #pragma unroll
      for(int m=0;m<4;m++)  af[m]  = *(const bf16x8*)&Abuf[(arb + m*16 + (l&15))*72 + kk*32 + (l>>4)*8];
      #pragma unroll
      for(int nf=0;nf<4;nf++) bfr[nf] = *(const bf16x8*)&Bbuf[(brb + nf*16 + (l&15))*72 + kk*32 + (l>>4)*8];
      #pragma unroll
      for(int m=0;m<4;m++)
        #pragma unroll
        for(int nf=0;nf<4;nf++)
          acc[m][nf] = mfma32(af[m], bfr[nf], acc[m][nf]);
    }
    __syncthreads();
  }

  int contrib = (nt*32 + b)*2 + wr;
  // ---- stat partials (register shuffles + race-free writes) ----
  if (mode < 2){
    #pragma unroll
    for(int nf=0;nf<4;nf++){
      int o = ob + wc*64 + nf*16 + (l&15);   // global channel (q:0-255, k:256-511)
      float s1=0.f, s2=0.f;
      #pragma unroll
      for(int m=0;m<4;m++){
        #pragma unroll
        for(int r=0;r<4;r++){
          float val = acc[m][nf][r];
          s1 += val; s2 += val*val;
        }
      }
      s1 += __shfl_xor(s1,16,64); s1 += __shfl_xor(s1,32,64);
      s2 += __shfl_xor(s2,16,64); s2 += __shfl_xor(s2,32,64);
      if (l < 16){
        float2 p; p.x = s1; p.y = s2;
        sqk[(size_t)o*512 + contrib] = p;
      }
    }
  } else {
    #pragma unroll
    for(int m=0;m<4;m++){
      #pragma unroll
      for(int r=0;r<4;r++){
        int o  = ob + wc*64 + m*16 + (l>>4)*4 + r;   // global 512..1023
        float s1=0.f, s2=0.f;
        #pragma unroll
        for(int nf=0;nf<4;nf++){
          float val = acc[m][nf][r];
          s1 += val; s2 += val*val;
        }
        s1 += __shfl_xor(s1,1,64); s1 += __shfl_xor(s1,2,64); s1 += __shfl_xor(s1,4,64); s1 += __shfl_xor(s1,8,64);
        s2 += __shfl_xor(s2,1,64); s2 += __shfl_xor(s2,2,64); s2 += __shfl_xor(s2,4,64); s2 += __shfl_xor(s2,8,64);
        if ((l&15)==0){
          float2 p; p.x = s1; p.y = s2;
          sqk[(size_t)o*512 + contrib] = p;
        }
      }
    }
  }

  // ---- epilogue: per-wave LDS transpose -> coalesced stores ----
  ushort* ep = smem + w*4608;
  if (mode < 2){
    #pragma unroll
    for(int m=0;m<4;m++)
      #pragma unroll
      for(int nf=0;nf<4;nf++){
        int lo = nf*16 + (l&15);
        #pragma unroll
        for(int r=0;r<4;r++){
          int ln = m*16 + (l>>4)*4 + r;
          ep[ln*72 + lo] = f2bf(acc[m][nf][r]);
        }
      }
    ushort* outb = (mode==0)? qb : kb;
    #pragma unroll
    for(int p=0;p<8;p++){
      int rr = p*8 + (l>>3);          // n-local
      int ci = (l&7)*8;               // o-local, 8-ch chunk
      uint4 v = *(const uint4*)&ep[rr*72 + ci];
      int n = nb + wr*64 + rr;
      int o = ob + wc*64 + ci;
      int oc = o & 255;
      int h = oc>>5, d = oc&31;
      *(uint4*)(outb + (((size_t)(b*8+h)<<10) + n)*32 + d) = v;
    }
  } else {
    #pragma unroll
    for(int m=0;m<4;m++)
      #pragma unroll
      for(int nf=0;nf<4;nf++){
        int ln = nf*16 + (l&15);
        #pragma unroll
        for(int r=0;r<4;r++){
          int lo = m*16 + (l>>4)*4 + r;
          ep[lo*72 + ln] = f2bf(acc[m][nf][r]);
        }
      }
    #pragma unroll
    for(int p=0;p<8;p++){
      int rr = p*8 + (l>>3);          // o-local
      int ci = (l&7)*8;               // n-local chunk
      uint4 v = *(const uint4*)&ep[rr*72 + ci];
      int o  = ob + wc*64 + rr;
      int ov = o - 512;
      int h = ov>>6, dv = ov&63;
      int n = nb + wr*64 + ci;
      *(uint4*)(vt + ((((size_t)b*8 + h)*64 + dv)<<10) + n) = v;
    }
  }
}

// ---------------- K3a: per-channel reduction + BN coefficients for q/k/v ----------------
__global__ __launch_bounds__(256) void k_coef(const float2* __restrict__ sqk,
    const float* gq, const float* bq, const float* gk, const float* bk,
    const float* gvp, const float* bvp, float* __restrict__ ab){
  __shared__ float red[4][2];
  int ch = blockIdx.x;
  int t = threadIdx.x, w = t>>6, l = t&63;
  float2 v0 = sqk[(size_t)ch*512 + t];
  float2 v1 = sqk[(size_t)ch*512 + 256 + t];
  float s1 = v0.x + v1.x, s2 = v0.y + v1.y;
  s1 += __shfl_xor(s1,1,64); s2 += __shfl_xor(s2,1,64);
  s1 += __shfl_xor(s1,2,64); s2 += __shfl_xor(s2,2,64);
  s1 += __shfl_xor(s1,4,64); s2 += __shfl_xor(s2,4,64);
  s1 += __shfl_xor(s1,8,64); s2 += __shfl_xor(s2,8,64);
  s1 += __shfl_xor(s1,16,64); s2 += __shfl_xor(s2,16,64);
  s1 += __shfl_xor(s1,32,64); s2 += __shfl_xor(s2,32,64);
  if (l==0){ red[w][0]=s1; red[w][1]=s2; }
  __syncthreads();
  if (t==0){
    float S1 = red[0][0]+red[1][0]+red[2][0]+red[3][0];
    float S2 = red[0][1]+red[1][1]+red[2][1]+red[3][1];
    float mean = S1 * (1.0f/32768.0f);
    float var  = S2 * (1.0f/32768.0f) - mean*mean;
    float inv  = rsqrtf(var + 1e-5f);
    float g, be, ex;
    if (ch < 256){ g = gq[ch]; be = bq[ch]; ex = 1.44269504088896f*0.17677669529664f; } // L2E*SCALE
    else if (ch < 512){ g = gk[ch-256]; be = bk[ch-256]; ex = 1.0f; }
    else { g = gvp[ch-512]; be = bvp[ch-512]; ex = 1.0f; }
    ab[ch*2]   = g*inv*ex;
    ab[ch*2+1] = (be - mean*g*inv)*ex;
  }
}

// q fragment prep: BN(q) then fold k's BN scale ak in; bk offset is dropped
// (constant along softmax rows -> cancels in P/l exactly).
__device__ __forceinline__ bf16x8 qprep(uint4 raw, const float* __restrict__ abq,
                                        const float* __restrict__ abk){
  uint w4[4] = {raw.x, raw.y, raw.z, raw.w};
  ushort o[8];
  #pragma unroll
  for(int p=0;p<4;p++){
    float lo = asf(w4[p]<<16), hi = asf(w4[p] & 0xffff0000u);
    float q0 = abq[p*4+0]*lo + abq[p*4+1];
    float q1 = abq[p*4+2]*hi + abq[p*4+3];
    o[p*2]   = f2bf(q0 * abk[p*4+0]);
    o[p*2+1] = f2bf(q1 * abk[p*4+2]);
  }
  bf16x8 r; __builtin_memcpy(&r, o, 16);
  return r;
}

// ---------------- K5: flash attention + fused q/k/v BN + gelu -> GT bf16 [b][n][512] ----------------
// R12 structure, minus kt LDS staging: K fragments load directly from kb
// (L2-hot — 8 itile blocks per (b,h) pinned to one XCD by h=bid&7).
// 2 i-strips per wave; l-sum via ones-MFMA.
__global__ __launch_bounds__(256) void k_attn(const ushort* __restrict__ qb, const ushort* __restrict__ kb,
    const ushort* __restrict__ vt, const ushort* __restrict__ bias,
    const float* __restrict__ ab, ushort* __restrict__ GT){
  __shared__ ushort smem[9216];       // vtl [2560,7168); gbuf overlays [0,9216)
  ushort* vtl = smem + 2560;
  ushort* gbuf = smem;
  int bid = blockIdx.x;
  int h = bid & 7;
  int itile = (bid>>3)&7;
  int b = bid>>6;
  int t = threadIdx.x, w = t>>6, l = t&63;
  int isub0 = itile*8 + w*2;          // two 16-row subtiles: isub0, isub0+1
  size_t bh = (size_t)b*8 + h;

  const float* abq = ab + (size_t)(h*32 + (l>>4)*8)*2;         // q BN coefs, 8 ch
  const float* abk = ab + (size_t)(256 + h*32 + (l>>4)*8)*2;   // k BN coefs (scale used)
  uint4 qr0 = *(const uint4*)(qb + ((bh<<10) + isub0*16 + (l&15))*32 + (l>>4)*8);
  uint4 qr1 = *(const uint4*)(qb + ((bh<<10) + (isub0+1)*16 + (l&15))*32 + (l>>4)*8);
  bf16x8 qf0 = qprep(qr0, abq, abk);
  bf16x8 qf1 = qprep(qr1, abq, abk);

  const shortx4 vones = { (short)0x3F80, (short)0x3F80, (short)0x3F80, (short)0x3F80 }; // bf16 1.0
  floatx4 lf0 = {0.f,0.f,0.f,0.f}, lf1 = {0.f,0.f,0.f,0.f};
  floatx4 O0[4] = {{0.f,0.f,0.f,0.f},{0.f,0.f,0.f,0.f},{0.f,0.f,0.f,0.f},{0.f,0.f,0.f,0.f}};
  floatx4 O1[4] = {{0.f,0.f,0.f,0.f},{0.f,0.f,0.f,0.f},{0.f,0.f,0.f,0.f},{0.f,0.f,0.f,0.f}};
  int sr = t>>2, scq = t&3;
  const uint2* bp0 = (const uint2*)bias + (((size_t)h*64 + isub0)*64)*64 + l;
  const uint2* bp1 = bp0 + 64*64;     // next isub
  const ushort* kfb = kb + (bh<<15) + (size_t)(l&15)*32 + (l>>4)*8;  // K frag base (per-lane)

  for(int jt=0;jt<16;jt++){
    int jbase = jt*64;
    const ushort* vsrc = vt + ((bh*64 + sr)<<10) + jbase + scq*16;
    *(uint4*)&vtl[sr*72 + scq*16]     = *(const uint4*)vsrc;
    *(uint4*)&vtl[sr*72 + scq*16 + 8] = *(const uint4*)(vsrc + 8);
    __syncthreads();

    #pragma unroll
    for(int js=0;js<4;js++){
      uint2 bw0 = bp0[js*64];
      uint2 bw1 = bp1[js*64];
      bf16x8 kf = *(const bf16x8*)(kfb + (size_t)(jbase + js*16)*32);
      floatx4 c0 = { asf(bw0.x<<16), asf(bw0.x & 0xffff0000u), asf(bw0.y<<16), asf(bw0.y & 0xffff0000u) };
      floatx4 c1 = { asf(bw1.x<<16), asf(bw1.x & 0xffff0000u), asf(bw1.y<<16), asf(bw1.y & 0xffff0000u) };
      floatx4 S0 = mfma32(kf, qf0, c0);   // S^T tile (j rows, i cols), log2 domain
      floatx4 S1 = mfma32(kf, qf1, c1);
      float a0 = __builtin_amdgcn_exp2f(S0[0]);
      float a1 = __builtin_amdgcn_exp2f(S0[1]);
      float a2 = __builtin_amdgcn_exp2f(S0[2]);
      float a3 = __builtin_amdgcn_exp2f(S0[3]);
      float b0 = __builtin_amdgcn_exp2f(S1[0]);
      float b1 = __builtin_amdgcn_exp2f(S1[1]);
      float b2 = __builtin_amdgcn_exp2f(S1[2]);
      float b3 = __builtin_amdgcn_exp2f(S1[3]);
      uint2 pu0, pu1;
      pu0.x = __builtin_amdgcn_perm(fbits(a1), fbits(a0), 0x07060302u);
      pu0.y = __builtin_amdgcn_perm(fbits(a3), fbits(a2), 0x07060302u);
      pu1.x = __builtin_amdgcn_perm(fbits(b1), fbits(b0), 0x07060302u);
      pu1.y = __builtin_amdgcn_perm(fbits(b3), fbits(b2), 0x07060302u);
      shortx4 p0, p1;
      __builtin_memcpy(&p0, &pu0, 8);
      __builtin_memcpy(&p1, &pu1, 8);
      lf0 = mfma16(vones, p0, lf0);       // column-sums of P -> l per i (col=lane&15)
      lf1 = mfma16(vones, p1, lf1);
      #pragma unroll
      for(int d=0;d<4;d++){
        shortx4 vf = *(const shortx4*)&vtl[(d*16 + (l&15))*72 + js*16 + (l>>4)*4];
        O0[d] = mfma16(vf, p0, O0[d]);    // out^T[dv][i], raw v (BN in epilogue)
        O1[d] = mfma16(vf, p1, O1[d]);
      }
    }
    bp0 += 256; bp1 += 256;   // 4 js * 64 lanes
    __syncthreads();
  }

  float invl0 = 1.0f/lf0[0];   // every reg/row of lf holds the same column sum
  float invl1 = 1.0f/lf1[0];

  // epilogue: v-BN (av*(O/l)+bv via l linearity), gelu, reorganize via LDS
  #pragma unroll
  for(int ii=0;ii<2;ii++){
    float invl = ii ? invl1 : invl0;
    #pragma unroll
    for(int d=0;d<4;d++){
      floatx4 Ov = ii ? O1[d] : O0[d];
      const float* abv = ab + (size_t)(512 + h*64 + d*16 + (l>>4)*4)*2;
      float4 e01 = *(const float4*)abv;
      float4 e23 = *(const float4*)(abv + 4);
      float av[4] = {e01.x, e01.z, e23.x, e23.z};
      float bv[4] = {e01.y, e01.w, e23.y, e23.w};
      ushort gu[4];
      #pragma unroll
      for(int r=0;r<4;r++){
        float o = av[r]*(Ov[r]*invl) + bv[r];
        float g = 0.5f*o*(1.0f + erff(o*0.70710678118655f));
        gu[r] = f2bf(g);
      }
      uint2 gw; gw.x = (uint)gu[0] | ((uint)gu[1]<<16); gw.y = (uint)gu[2] | ((uint)gu[3]<<16);
      *(uint2*)&gbuf[w*2304 + (ii*16 + (l&15))*72 + d*16 + (l>>4)*4] = gw;
    }
  }
  __syncthreads();
  int ibase = itile*128 + w*32;
  #pragma unroll
  for(int p8=0;p8<4;p8++){
    int rl = (l>>3) + p8*8;
    int ck = l&7;
    uint4 g4 = *(uint4*)&gbuf[w*2304 + rl*72 + ck*8];
    int n = ibase + rl;
    *(uint4*)(GT + ((size_t)(b*1024 + n))*512 + h*64 + ck*8) = g4;
  }
}

// ---------------- K6: output conv + bias + stat partials (BK=64, NO atomics) ----------------
__global__ __launch_bounds__(256) void k_oconv(const ushort* __restrict__ GT, const float* __restrict__ Wo,
    const float* __restrict__ bo, ushort* __restrict__ opre, float2* __restrict__ soc){
  __shared__ ushort smem[18432];      // Aw [0,9216) | Ag [9216,18432)
  ushort* Aw = smem;
  ushort* Ag = smem + 9216;
  int bid = blockIdx.x;
  int nt = bid & 15; int ot = (bid>>4)&3; int b = bid>>6;
  int nb = nt*64, ob = ot*64;
  int t = threadIdx.x, w = t>>6, l = t&63;
  int sr = t>>2, sc = (t&3)*16;
  const float*  wsrc = Wo + (size_t)(ob + sr)*512 + sc;
  const ushort* gsrc = GT + ((size_t)b*1024 + nb + sr)*512 + sc;
  floatx4 acc[4] = {{0.f,0.f,0.f,0.f},{0.f,0.f,0.f,0.f},{0.f,0.f,0.f,0.f},{0.f,0.f,0.f,0.f}};
  for(int kc=0;kc<8;kc++){
    *(uint4*)&Aw[sr*72+sc]   = cvt8(wsrc + kc*64);
    *(uint4*)&Aw[sr*72+sc+8] = cvt8(wsrc + kc*64 + 8);
    *(uint4*)&Ag[sr*72+sc]   = *(const uint4*)(gsrc + kc*64);
    *(uint4*)&Ag[sr*72+sc+8] = *(const uint4*)(gsrc + kc*64 + 8);
    __syncthreads();
    #pragma unroll
    for(int kk=0;kk<2;kk++){
      bf16x8 af = *(const bf16x8*)&Aw[(w*16 + (l&15))*72 + kk*32 + (l>>4)*8];
      #pragma unroll
      for(int ns=0;ns<4;ns++){
        bf16x8 bfv = *(const bf16x8*)&Ag[(ns*16 + (l&15))*72 + kk*32 + (l>>4)*8];
        acc[ns] = mfma32(af, bfv, acc[ns]);
      }
    }
    __syncthreads();
  }
  // ---- stats + per-wave LDS transpose (Aw/Ag dead after final barrier) ----
  ushort* ep = smem + w*1152;          // 16 rows x 72 ushorts per wave
  int contrib = nt*32 + b;             // 512 contributors per channel
  #pragma unroll
  for(int r_=0;r_<4;r_++){
    int o = ob + w*16 + (l>>4)*4 + r_;
    float bias_o = bo[o];
    float s1=0.f, s2=0.f;
    #pragma unroll
    for(int ns=0;ns<4;ns++){
      float val = acc[ns][r_] + bias_o;
      ep[((l>>4)*4 + r_)*72 + ns*16 + (l&15)] = f2bf(val);
      s1 += val; s2 += val*val;
    }
    s1 += __shfl_xor(s1,1,64); s1 += __shfl_xor(s1,2,64); s1 += __shfl_xor(s1,4,64); s1 += __shfl_xor(s1,8,64);
    s2 += __shfl_xor(s2,1,64); s2 += __shfl_xor(s2,2,64); s2 += __shfl_xor(s2,4,64); s2 += __shfl_xor(s2,8,64);
    if ((l&15)==0){
      float2 p; p.x = s1; p.y = s2;
      soc[(size_t)o*512 + contrib] = p;
    }
  }
  // in-wave DS ordering -> no barrier needed; coalesced 2x16B stores per lane
  {
    int rr = l>>2, cseg = (l&3)*16;
    uint4 v0 = *(const uint4*)&ep[rr*72 + cseg];
    uint4 v1 = *(const uint4*)&ep[rr*72 + cseg + 8];
    int o = ob + w*16 + rr;
    ushort* dst = opre + (((size_t)(b*256+o))<<10) + nb + cseg;
    *(uint4*)dst     = v0;
    *(uint4*)(dst+8) = v1;
  }
}

// ---------------- K6b: per-channel reduction + final BN coefs ----------------
__global__ __launch_bounds__(256) void k_ocoef(const float2* __restrict__ soc,
    const float* __restrict__ go, const float* __restrict__ beo, float* __restrict__ oc){
  __shared__ float red[4][2];
  int ch = blockIdx.x;
  int t = threadIdx.x, w = t>>6, l = t&63;
  float2 v0 = soc[(size_t)ch*512 + t];
  float2 v1 = soc[(size_t)ch*512 + 256 + t];
  float s1 = v0.x + v1.x, s2 = v0.y + v1.y;
  s1 += __shfl_xor(s1,1,64); s2 += __shfl_xor(s2,1,64);
  s1 += __shfl_xor(s1,2,64); s2 += __shfl_xor(s2,2,64);
  s1 += __shfl_xor(s1,4,64); s2 += __shfl_xor(s2,4,64);
  s1 += __shfl_xor(s1,8,64); s2 += __shfl_xor(s2,8,64);
  s1 += __shfl_xor(s1,16,64); s2 += __shfl_xor(s2,16,64);
  s1 += __shfl_xor(s1,32,64); s2 += __shfl_xor(s2,32,64);
  if (l==0){ red[w][0]=s1; red[w][1]=s2; }
  __syncthreads();
  if (t==0){
    float S1 = red[0][0]+red[1][0]+red[2][0]+red[3][0];
    float S2 = red[0][1]+red[1][1]+red[2][1]+red[3][1];
    float mean = S1 * (1.0f/32768.0f);
    float var  = S2 * (1.0f/32768.0f) - mean*mean;
    float inv  = rsqrtf(var + 1e-5f);
    float a = go[ch]*inv;
    oc[ch*2]   = a;
    oc[ch*2+1] = beo[ch] - mean*a;
  }
}

// ---------------- K7: final BN apply (coefs precomputed; bf16 in, f32 out) ----------------
__global__ __launch_bounds__(256) void k_bnout(const ushort* __restrict__ opre, const float* __restrict__ oc,
    float* __restrict__ out){
  size_t e = ((size_t)blockIdx.x*256 + threadIdx.x)*4;
  int o = (int)((e>>10)&255);
  float a = oc[o*2], bb = oc[o*2+1];
  uint2 raw = *(const uint2*)(opre + e);
  float4 ov;
  ov.x = a*asf(raw.x<<16)           + bb;
  ov.y = a*asf(raw.x & 0xffff0000u) + bb;
  ov.z = a*asf(raw.y<<16)           + bb;
  ov.w = a*asf(raw.y & 0xffff0000u) + bb;
  *(float4*)(out + e) = ov;
}

extern "C" void kernel_launch(void* const* d_in, const int* in_sizes, int n_in,
                              void* d_out, int out_size, void* d_ws, size_t ws_size,
                              hipStream_t stream){
  (void)in_sizes; (void)n_in; (void)out_size;
  const float* x   = (const float*)d_in[0];
  const float* Wq  = (const float*)d_in[1];
  const float* gq  = (const float*)d_in[2];
  const float* bq  = (const float*)d_in[3];
  const float* Wk  = (const float*)d_in[4];
  const float* gk  = (const float*)d_in[5];
  const float* bk  = (const float*)d_in[6];
  const float* Wv  = (const float*)d_in[7];
  const float* gvp = (const float*)d_in[8];
  const float* bvp = (const float*)d_in[9];
  const float* Wo  = (const float*)d_in[10];
  const float* bo  = (const float*)d_in[11];
  const float* go  = (const float*)d_in[12];
  const float* beo = (const float*)d_in[13];
  const float* pt  = (const float*)d_in[14];
  // d_in[15] pos_indices: unused (recomputed analytically)

  char* ws = (char*)d_ws;
  if (ws_size < (size_t)WS_NEED) return;
  ushort* qb   = (ushort*)(ws);
  ushort* kb   = (ushort*)(ws + OFF_KB);
  ushort* vt   = (ushort*)(ws + OFF_VT);
  ushort* bias = (ushort*)(ws + OFF_BIAS);
  ushort* xT   = (ushort*)(ws + OFF_XT);
  ushort* wbf  = (ushort*)(ws + OFF_WBF);
  ushort* GT   = (ushort*)(ws + OFF_GT);
  ushort* opre = (ushort*)(ws);
  float2* sqk  = (float2*)(ws + OFF_SQK);     // dead GT tail until k_attn
  float2* soc  = (float2*)(ws + OFF_KB);      // kb region, dead after k_attn
  float* oc    = (float*)(ws + OFF_OSUM);
  float* ab    = (float*)(ws + OFF_AB);

  k_prep<<<10496,256,0,stream>>>(x, Wq, Wk, Wv, pt, xT, wbf, bias);
  k_qkv<<<2048,256,0,stream>>>(xT, wbf, qb, kb, vt, sqk);
  k_coef<<<1024,256,0,stream>>>(sqk, gq, bq, gk, bk, gvp, bvp, ab);
  k_attn<<<2048,256,0,stream>>>(qb, kb, vt, bias, ab, GT);
  k_oconv<<<2048,256,0,stream>>>(GT, Wo, bo, opre, soc);
  k_ocoef<<<256,256,0,stream>>>(soc, go, beo, oc);
  k_bnout<<<8192,256,0,stream>>>(opre, oc, (float*)d_out);
}